// Round 1
// baseline (514.195 us; speedup 1.0000x reference)
//
#include <hip/hip_runtime.h>

typedef _Float16 h4 __attribute__((ext_vector_type(4)));
typedef _Float16 h8 __attribute__((ext_vector_type(8)));
typedef float f4 __attribute__((ext_vector_type(4)));

#define CIN 256
#define HID 256
#define HWSZ 16384
#define NT 64

// Pre-kernel: W1f[m][k] = (f16) W1^T  and  W2f[m][k] = (f16) W2^T, stored in
// MFMA A-fragment order so the hot loop reads frags with one global_load_dwordx4.
// fidx(m,k) = (k>>5)*8192 + (m>>4)*512 + ((k>>3)&3)*128 + (m&15)*8 + (k&7)
__global__ __launch_bounds__(256) void wconv_kernel(const float* __restrict__ W1,
                                                    const float* __restrict__ W2,
                                                    _Float16* __restrict__ W1f,
                                                    _Float16* __restrict__ W2f) {
  int t = blockIdx.x * 256 + threadIdx.x;  // 0..65535
  int m = t & 255;                          // output-row index (d for W1, c for W2)
  int k = t >> 8;                           // reduction index  (c for W1, d for W2)
  int fi = ((k >> 5) << 13) | ((m >> 4) << 9) | (((k >> 3) & 3) << 7) |
           ((m & 15) << 3) | (k & 7);
  W1f[fi] = (_Float16)W1[k * 256 + m];  // A1[d][c] = W1[c][d]
  W2f[fi] = (_Float16)W2[k * 256 + m];  // A2[c][d] = W2[d][c]
}

__global__ __launch_bounds__(256, 2) void mlp_kernel(
    const float* __restrict__ in, const int* __restrict__ mask,
    const float* __restrict__ b1, const float* __restrict__ b2,
    const _Float16* __restrict__ W1f, const _Float16* __restrict__ W2f,
    float* __restrict__ out) {
  // LDS: X tile and H tile, f16, [n][c] with XOR swizzle; exactly 64 KB total.
  __shared__ alignas(16) _Float16 Xs[NT * 256];
  __shared__ alignas(16) _Float16 Hs[NT * 256];

  const int t = threadIdx.x;
  const int g = blockIdx.x;
  const int b = g >> 8;              // 256 tiles per batch image (16384/64)
  const int hw0 = (g & 255) * NT;
  const float* inb = in + (size_t)b * CIN * HWSZ + hw0;

  // ---- stage X (fp32 global -> f16 LDS, transposed to [n][c]) ----
  {
    const int n = t & 63;
    const int cg = (t >> 6) * 4;          // wave id * 4
    const int sw = (n & 7) << 3;
#pragma unroll
    for (int i = 0; i < 16; ++i) {
      const int c0 = i * 16 + cg;
      float x0 = inb[(size_t)(c0 + 0) * HWSZ + n];
      float x1 = inb[(size_t)(c0 + 1) * HWSZ + n];
      float x2 = inb[(size_t)(c0 + 2) * HWSZ + n];
      float x3 = inb[(size_t)(c0 + 3) * HWSZ + n];
      h4 xv;
      xv[0] = (_Float16)x0; xv[1] = (_Float16)x1;
      xv[2] = (_Float16)x2; xv[3] = (_Float16)x3;
      *(h4*)&Xs[n * 256 + (c0 ^ sw)] = xv;   // 8B-aligned ds_write_b64
    }
  }
  __syncthreads();

  const int w = t >> 6;     // wave 0..3 -> M rows [64w, 64w+64)
  const int l = t & 63;
  const int li = l & 15;    // n (B/D col) / m (A row) within tile
  const int q = l >> 4;     // quad

  f4 acc[4][4];
#pragma unroll
  for (int mt = 0; mt < 4; ++mt)
#pragma unroll
    for (int nt = 0; nt < 4; ++nt)
#pragma unroll
      for (int r = 0; r < 4; ++r) acc[mt][nt][r] = 0.f;

  // ---- GEMM1: H = relu(W1^T X + b1) ----
#pragma unroll 2
  for (int kc = 0; kc < 8; ++kc) {
    h8 af[4], bf[4];
#pragma unroll
    for (int mt = 0; mt < 4; ++mt)
      af[mt] = *(const h8*)(W1f + (kc << 13) + ((4 * w + mt) << 9) + (l << 3));
#pragma unroll
    for (int nt = 0; nt < 4; ++nt) {
      const int nn = nt * 16 + li;
      bf[nt] = *(const h8*)&Xs[nn * 256 + (((kc << 5) + (q << 3)) ^ ((nn & 7) << 3))];
    }
#pragma unroll
    for (int mt = 0; mt < 4; ++mt)
#pragma unroll
      for (int nt = 0; nt < 4; ++nt)
        acc[mt][nt] = __builtin_amdgcn_mfma_f32_16x16x32_f16(af[mt], bf[nt], acc[mt][nt], 0, 0, 0);
  }

  // ---- epilogue 1: bias + relu, write Hs ----
#pragma unroll
  for (int mt = 0; mt < 4; ++mt) {
    const int d0 = w * 64 + mt * 16 + q * 4;
    const f4 bb = *(const f4*)(b1 + d0);
#pragma unroll
    for (int nt = 0; nt < 4; ++nt) {
      const int nn = nt * 16 + li;
      h4 hv;
#pragma unroll
      for (int r = 0; r < 4; ++r) {
        float v = acc[mt][nt][r] + bb[r];
        hv[r] = (_Float16)(v > 0.f ? v : 0.f);
      }
      *(h4*)&Hs[nn * 256 + (d0 ^ ((nn & 7) << 3))] = hv;
    }
  }
  __syncthreads();

  // ---- GEMM2: Y = W2^T H + b2 ----
#pragma unroll
  for (int mt = 0; mt < 4; ++mt)
#pragma unroll
    for (int nt = 0; nt < 4; ++nt)
#pragma unroll
      for (int r = 0; r < 4; ++r) acc[mt][nt][r] = 0.f;

#pragma unroll 2
  for (int kc = 0; kc < 8; ++kc) {
    h8 af[4], bf[4];
#pragma unroll
    for (int mt = 0; mt < 4; ++mt)
      af[mt] = *(const h8*)(W2f + (kc << 13) + ((4 * w + mt) << 9) + (l << 3));
#pragma unroll
    for (int nt = 0; nt < 4; ++nt) {
      const int nn = nt * 16 + li;
      bf[nt] = *(const h8*)&Hs[nn * 256 + (((kc << 5) + (q << 3)) ^ ((nn & 7) << 3))];
    }
#pragma unroll
    for (int mt = 0; mt < 4; ++mt)
#pragma unroll
      for (int nt = 0; nt < 4; ++nt)
        acc[mt][nt] = __builtin_amdgcn_mfma_f32_16x16x32_f16(af[mt], bf[nt], acc[mt][nt], 0, 0, 0);
  }

  // ---- epilogue 2: bias + mask select + store ----
  const int* mb = mask + b * HWSZ + hw0;
  int mv[4];
#pragma unroll
  for (int nt = 0; nt < 4; ++nt) mv[nt] = mb[nt * 16 + li];

  float* outb = out + (size_t)b * CIN * HWSZ + hw0;
#pragma unroll
  for (int ct = 0; ct < 4; ++ct) {
    const int c0 = w * 64 + ct * 16 + q * 4;
    const f4 bb = *(const f4*)(b2 + c0);
#pragma unroll
    for (int nt = 0; nt < 4; ++nt) {
      const int nn = nt * 16 + li;
      const h4 xv = *(const h4*)&Xs[nn * 256 + (c0 ^ ((nn & 7) << 3))];
#pragma unroll
      for (int r = 0; r < 4; ++r) {
        float y = acc[ct][nt][r] + bb[r];
        outb[(size_t)(c0 + r) * HWSZ + nn] = mv[nt] ? y : (float)xv[r];
      }
    }
  }
}

extern "C" void kernel_launch(void* const* d_in, const int* in_sizes, int n_in,
                              void* d_out, int out_size, void* d_ws, size_t ws_size,
                              hipStream_t stream) {
  const float* in = (const float*)d_in[0];
  const int* mask = (const int*)d_in[1];
  const float* W1 = (const float*)d_in[2];
  const float* b1 = (const float*)d_in[3];
  const float* W2 = (const float*)d_in[4];
  const float* b2 = (const float*)d_in[5];
  float* out = (float*)d_out;

  _Float16* W1f = (_Float16*)d_ws;              // 65536 f16 = 128 KB
  _Float16* W2f = W1f + 65536;                  // next 128 KB (ws_size >= 256 KB)

  hipLaunchKernelGGL(wconv_kernel, dim3(256), dim3(256), 0, stream, W1, W2, W1f, W2f);
  hipLaunchKernelGGL(mlp_kernel, dim3(16 * (HWSZ / NT)), dim3(256), 0, stream,
                     in, mask, b1, b2, W1f, W2f, out);
}